// Round 12
// baseline (101.294 us; speedup 1.0000x reference)
//
#include <hip/hip_runtime.h>

// ---------- types ----------
typedef __attribute__((ext_vector_type(8))) short short8;     // 8 bf16 (4 VGPRs)
typedef __attribute__((ext_vector_type(4))) float floatx4;    // MFMA C/D
typedef __attribute__((ext_vector_type(4))) unsigned int uintx4;

// ---------- fp32 -> packed bf16x2 (RNE) ----------
#if __has_builtin(__builtin_amdgcn_cvt_pk_bf16_f32)
typedef __attribute__((ext_vector_type(2))) __bf16 bf16x2;
__device__ __forceinline__ unsigned int pk_bf16(float a, float b) {
  bf16x2 v = __builtin_amdgcn_cvt_pk_bf16_f32(a, b);
  return __builtin_bit_cast(unsigned int, v);
}
#else
__device__ __forceinline__ unsigned int bf16_1(float f) {
  unsigned int u = __builtin_bit_cast(unsigned int, f);
  return (u + 0x7fffu + ((u >> 16) & 1u)) >> 16;
}
__device__ __forceinline__ unsigned int pk_bf16(float a, float b) {
  return bf16_1(a) | (bf16_1(b) << 16);
}
#endif

// Fragment conventions (verified rounds 0-11, absmax 3.9e-3):
//   A-frag (16x16x32): lane(ln,quad) holds A[m=ln][k=quad*8+j], j=0..7
//   B-frag:            lane(ln,quad) holds B[n=ln][k=quad*8+j]  (B[k][n]=W[c][r][k], n=r*8+c)
//   C/D:               col=ln, row=quad*4+reg
// Bprep frag id: Fb = ((mod*8 + h)*24 + ks)*4 + nt, n16 = h*4+nt; frag = 64 lanes x 16B.
//
// LEDGER OF DEAD ENDS (do not revisit without new evidence):
// * STORE GEOMETRY LOAD-BEARING: scalar dword stores, 16 consecutive dwords
//   per 16-lane group x 4 rows/instr = 1.0x writes. Anything else 1.5-3.0x.
// * NONTEMPORAL hints: hurt both directions.
// * PERMUTED-B + direct stores: silent transpose (round 6).
// * REG-SPILL SIGNATURE: WRITE 612 MB / FETCH 211 MB / 2.4x dur (round 7).
// * 64-ROW 16-WAVE BLOCKS: quantization tax 2+1 blocks/CU (round 9).
// * OCCUPANCY 43->76%: zero effect (round 10). TLP is not the limiter.
// * PREFETCH DEPTH 2->3: zero effect (round 11). ~100cy cover vs ~250cy
//   latency; deeper spills. Per-wave ILP is not the limiter.
// ROUND-12 HYPOTHESIS: L2 BW (~18 TB/s sustained vs ~20 effective ceiling)
// is binding. Test cleanly: 64x256 blocks, 8 waves = 2 row-halves x 4
// col-groups; wave pairs read IDENTICAL B-slices in identical (staggered)
// order -> MSHR merge halves B L2 traffic; no quantization change.

// ============================================================
// Prepass W: [8][64][768] fp32 -> bf16 B-fragments; bias permuted to n-order.
// ============================================================
__global__ __launch_bounds__(256) void prep_w(
    const float* __restrict__ Wi, const float* __restrict__ Wc, const float* __restrict__ Wd,
    const float* __restrict__ bi, const float* __restrict__ bc, const float* __restrict__ bd,
    uintx4* __restrict__ Bprep, float* __restrict__ biasPrep) {
  const int t = blockIdx.x * 256 + threadIdx.x;  // 0 .. 147455
  const int l = t & 63;
  const int frag = t >> 6;             // 0 .. 2303
  const int nt = frag & 3;
  const int q = frag >> 2;
  const int ks = q % 24;
  const int q2 = q / 24;
  const int h = q2 & 7;
  const int mod = q2 >> 3;
  const int n16 = h * 4 + nt;
  const float* __restrict__ W = (mod == 0) ? Wi : ((mod == 1) ? Wc : Wd);

  const int n = n16 * 16 + (l & 15);
  const int r = n >> 3;
  const int c = n & 7;
  const int i0 = ks * 32 + (l >> 4) * 8;
  const float* src = W + (size_t)(c * 64 + r) * 768 + i0;
  floatx4 f0 = *(const floatx4*)(src);
  floatx4 f1 = *(const floatx4*)(src + 4);
  uintx4 p;
  p.x = pk_bf16(f0.x, f0.y);
  p.y = pk_bf16(f0.z, f0.w);
  p.z = pk_bf16(f1.x, f1.y);
  p.w = pk_bf16(f1.z, f1.w);
  Bprep[(size_t)frag * 64 + l] = p;

  if (t < 1536) {
    const int m2 = t >> 9;
    const int nn = t & 511;
    const float* bb = (m2 == 0) ? bi : ((m2 == 1) ? bc : bd);
    biasPrep[t] = bb[(nn & 7) * 64 + (nn >> 3)];
  }
}

// ============================================================
// Fused GEMM + squash, 64x256 blocks with B-sharing wave pairs.
//   Block: 512 thr / 8 waves = 2 row-halves (wr) x 4 col-groups (wc).
//   Wave tile 32x64 (acc[2][4] = 32 AGPR, ~100 regs total, (512,4) cap 128).
//   A staged in two K-phases (64 rows x 384 cols bf16 = 48 KB, slot-XOR),
//   3 barriers; 2-deep register prefetch inside each phase.
//   Wave pair (wr=0/1, same wc) reads the SAME B-frags in the SAME
//   (wc-staggered) step order -> L2 MSHR merge halves B traffic.
//   Grid 1536 = 3 mods x 2 col-halves x 256 row-tiles (XCD swizzle 8x192;
//   3 blocks/CU x 2 clean rounds).
//   Epilogue: shuffle-squash + rsq/rcp + proven 1.0x store geometry.
// ============================================================
#define STAGE(p)                                                              \
  {                                                                           \
    _Pragma("unroll") for (int i = 0; i < 12; ++i) {                          \
      const int idx = i * 2048 + tid * 4;        /* flat in 64x384 tile */    \
      const int m = (unsigned)idx / 384u;                                     \
      const int k = idx - m * 384;                                            \
      floatx4 f = *(const floatx4*)(srcb + (size_t)m * 768 + (p) * 384 + k);  \
      const int ks2 = k >> 5;                    /* local K-step 0..11 */     \
      const int kk = k & 31;                                                  \
      const int qk = kk >> 3;                                                 \
      const int jh = (kk >> 2) & 1;                                           \
      const int mg = m >> 4;                     /* 16-row group 0..3 */      \
      const int lnn = m & 15;                                                 \
      const int px = (ks2 * 4 + qk) & 15;        /* slot-XOR spread */        \
      const int slot = (lnn ^ px) + (qk << 4);                                \
      unsigned long long w =                                                  \
          ((unsigned long long)pk_bf16(f.z, f.w) << 32) | pk_bf16(f.x, f.y);  \
      As64[(((ks2 * 4 + mg) * 64 + slot) << 1) + jh] = w;                     \
    }                                                                         \
  }

#define LOADA(aa, kk) /* kk = LOCAL K-step 0..11 */                          \
  {                                                                          \
    _Pragma("unroll") for (int mt = 0; mt < 2; ++mt)                         \
        aa[mt] = Afr[((kk) * 4 + wr2 + mt) * 64 +                            \
                     ((ln ^ (((kk) * 4 + quad) & 15)) + (quad << 4))];       \
  }

#define LOADB(bb, kk) /* kk = GLOBAL K-step 0..23 */                         \
  {                                                                          \
    _Pragma("unroll") for (int n2 = 0; n2 < 4; ++n2)                         \
        bb[n2] = bbase[(size_t)((kk) * 4 + n2) * 64];                        \
  }

#define COMP(aa, bb)                                                     \
  {                                                                      \
    _Pragma("unroll") for (int mt = 0; mt < 2; ++mt)                     \
    {                                                                    \
      short8 af = __builtin_bit_cast(short8, aa[mt]);                    \
      _Pragma("unroll") for (int n2 = 0; n2 < 4; ++n2)                   \
          acc[mt][n2] = __builtin_amdgcn_mfma_f32_16x16x32_bf16(         \
              af, __builtin_bit_cast(short8, bb[n2]), acc[mt][n2], 0, 0, \
              0);                                                        \
    }                                                                    \
  }

#define INCW(u) { u = (u == 11) ? 0 : (u + 1); }

__global__ __launch_bounds__(512, 4) void caps_fused(
    const float* __restrict__ x0, const float* __restrict__ x1, const float* __restrict__ x2,
    const uintx4* __restrict__ Bprep, const float* __restrict__ biasPrep,
    float* __restrict__ out) {
  __shared__ unsigned long long As64[48 * 128];  // 48 frags x 64 slots x 16 B

  const int tid = threadIdx.x;
  // XCD-chunk swizzle: 1536 = 8 XCDs x 192 contiguous blocks (bijective).
  const int bx0 = blockIdx.x;
  const int bx = (bx0 & 7) * 192 + (bx0 >> 3);
  const int mod = bx >> 9;           // 3 mods
  const int ch = (bx >> 8) & 1;      // col-half (256 cols)
  const int bm = bx & 255;           // 64-row tile
  const float* __restrict__ X = (mod == 0) ? x0 : ((mod == 1) ? x1 : x2);
  const float* srcb = X + (size_t)bm * 64 * 768;

  const int lane = tid & 63;
  const int ln = lane & 15;
  const int quad = lane >> 4;
  const int wv = tid >> 6;           // 0..7
  const int wr = wv >> 2;            // row-half
  const int wc = wv & 3;             // col-group
  const int wr2 = wr << 1;

  const uintx4* Afr = (const uintx4*)As64;
  const uintx4* bbase =
      Bprep + (size_t)(mod * 8 + ch * 4 + wc) * (24 * 4 * 64) + lane;

  floatx4 acc[2][4] = {};
  uintx4 a0[2], a1[2], b0[4], b1[4];
  const int s0 = wc * 3;             // per-col-group stagger (pairs match)

  // ---- phase 0: K 0..383 ----
  STAGE(0);
  __syncthreads();
  int u = s0;
  LOADA(a0, u); LOADB(b0, u); INCW(u);
#pragma unroll 1
  for (int j = 0; j < 6; ++j) {
    LOADA(a1, u); LOADB(b1, u); INCW(u);
    COMP(a0, b0);
    if (j != 5) { LOADA(a0, u); LOADB(b0, u); INCW(u); }
    COMP(a1, b1);
  }

  // ---- phase 1: K 384..767; prefetch its first B before restage ----
  LOADB(b0, 12 + s0);   // global only, safe across barriers
  __syncthreads();      // WAR: phase-0 ds_reads complete
  STAGE(1);
  __syncthreads();
  u = s0;
  LOADA(a0, u); INCW(u);
#pragma unroll 1
  for (int j = 0; j < 6; ++j) {
    LOADA(a1, u); LOADB(b1, 12 + u); INCW(u);
    COMP(a0, b0);
    if (j != 5) { LOADA(a0, u); LOADB(b0, 12 + u); INCW(u); }
    COMP(a1, b1);
  }

  // ---- epilogue: bias + squash (8 capsule lanes share s) + store ----
  const int col0 = mod * 512 + ch * 256 + wc * 64 + ln;
  float bias[4];
#pragma unroll
  for (int n2 = 0; n2 < 4; ++n2) bias[n2] = biasPrep[col0 + n2 * 16];

#pragma unroll
  for (int mt = 0; mt < 2; ++mt) {
    const size_t rbase =
        (size_t)(bm * 64 + wr * 32 + mt * 16 + quad * 4) * 1536;
#pragma unroll
    for (int n2 = 0; n2 < 4; ++n2) {
      float* op = out + rbase + col0 + n2 * 16;
#pragma unroll
      for (int jj = 0; jj < 4; ++jj) {
        float uo = acc[mt][n2][jj] + bias[n2];
        float s = uo * uo;
        s += __shfl_xor(s, 1);
        s += __shfl_xor(s, 2);
        s += __shfl_xor(s, 4);
#if __has_builtin(__builtin_amdgcn_rsqf) && __has_builtin(__builtin_amdgcn_rcpf)
        float sc = s * __builtin_amdgcn_rsqf(s + 1e-7f) *
                   __builtin_amdgcn_rcpf(1.0f + s);
#else
        float sc = s / ((1.0f + s) * sqrtf(s + 1e-7f));
#endif
        op[(size_t)jj * 1536] = uo * sc;
      }
    }
  }
}

// ============================================================
extern "C" void kernel_launch(void* const* d_in, const int* in_sizes, int n_in,
                              void* d_out, int out_size, void* d_ws, size_t ws_size,
                              hipStream_t stream) {
  const float* ximg = (const float*)d_in[0];
  const float* xcapt = (const float*)d_in[1];
  const float* xdct = (const float*)d_in[2];
  const float* Wi = (const float*)d_in[3];
  const float* bi = (const float*)d_in[4];
  const float* Wc = (const float*)d_in[5];
  const float* bc = (const float*)d_in[6];
  const float* Wd = (const float*)d_in[7];
  const float* bd = (const float*)d_in[8];

  uintx4* Bprep = (uintx4*)d_ws;                           // 2.25 MiB
  float* biasPrep = (float*)((char*)d_ws + 2304 * 1024);   // 6 KiB

  hipLaunchKernelGGL(prep_w, dim3(576), dim3(256), 0, stream,
                     Wi, Wc, Wd, bi, bc, bd, Bprep, biasPrep);
  hipLaunchKernelGGL(caps_fused, dim3(1536), dim3(512), 0, stream,
                     ximg, xcapt, xdct, (const uintx4*)Bprep, biasPrep,
                     (float*)d_out);
}

// Round 13
// 83.579 us; speedup vs baseline: 1.2119x; 1.2119x over previous
//
#include <hip/hip_runtime.h>

// ---------- types ----------
typedef __attribute__((ext_vector_type(8))) short short8;     // 8 bf16 (4 VGPRs)
typedef __attribute__((ext_vector_type(4))) float floatx4;    // MFMA C/D
typedef __attribute__((ext_vector_type(4))) unsigned int uintx4;

// ---------- fp32 -> packed bf16x2 (RNE) ----------
#if __has_builtin(__builtin_amdgcn_cvt_pk_bf16_f32)
typedef __attribute__((ext_vector_type(2))) __bf16 bf16x2;
__device__ __forceinline__ unsigned int pk_bf16(float a, float b) {
  bf16x2 v = __builtin_amdgcn_cvt_pk_bf16_f32(a, b);
  return __builtin_bit_cast(unsigned int, v);
}
#else
__device__ __forceinline__ unsigned int bf16_1(float f) {
  unsigned int u = __builtin_bit_cast(unsigned int, f);
  return (u + 0x7fffu + ((u >> 16) & 1u)) >> 16;
}
__device__ __forceinline__ unsigned int pk_bf16(float a, float b) {
  return bf16_1(a) | (bf16_1(b) << 16);
}
#endif

// Fragment conventions (verified rounds 0-12, absmax 3.9e-3):
//   A-frag (16x16x32): lane(ln,quad) holds A[m=ln][k=quad*8+j], j=0..7
//   B-frag:            lane(ln,quad) holds B[n=ln][k=quad*8+j]  (B[k][n]=W[c][r][k], n=r*8+c)
//   C/D:               col=ln, row=quad*4+reg
// Bprep frag id: Fb = ((mod*8 + h)*24 + ks)*4 + nt, n16 = h*4+nt; frag = 64 lanes x 16B.
//
// LEDGER OF DEAD ENDS (do not revisit without new evidence):
// * STORE GEOMETRY LOAD-BEARING: scalar dword stores, 16 consecutive dwords
//   per 16-lane group x 4 rows/instr = 1.0x writes. Anything else 1.5-3.0x.
// * NONTEMPORAL hints: hurt both directions.
// * PERMUTED-B + direct stores: silent transpose (round 6).
// * REG-SPILL SIGNATURE: WRITE 612 MB / FETCH 211 MB / 2.4x dur (round 7).
// * 64-ROW 16-WAVE BLOCKS: quantization tax (round 9).
// * OCCUPANCY 43->76%: zero effect (round 10). TLP is not the limiter.
// * PREFETCH DEPTH 2->3: zero effect (round 11). Per-wave ILP not the limiter.
// * 64x256 COL-SPLIT BLOCKS: X HBM reads double (FETCH 82->154 MB, L3 does
//   NOT absorb); staging VALU doubles; net +20 us (round 12).
// ROUND-13 HYPOTHESIS: CONVOYING. All waves leave the barrier together and
// run the SAME K-step schedule -> synchronized B-load bursts + synchronized
// vmcnt stalls (Little's law: only ~7 outstanding wave-loads/CU needed for
// observed throughput vs 96 possible -> waves burst-then-idle in lockstep).
// Fix: per-wave K-start stagger wv*3 (waves own disjoint B-slices; K-sum
// commutes -> numerics unchanged, r12 confirmed).

// ============================================================
// Prepass W: [8][64][768] fp32 -> bf16 B-fragments; bias permuted to n-order.
// ============================================================
__global__ __launch_bounds__(256) void prep_w(
    const float* __restrict__ Wi, const float* __restrict__ Wc, const float* __restrict__ Wd,
    const float* __restrict__ bi, const float* __restrict__ bc, const float* __restrict__ bd,
    uintx4* __restrict__ Bprep, float* __restrict__ biasPrep) {
  const int t = blockIdx.x * 256 + threadIdx.x;  // 0 .. 147455
  const int l = t & 63;
  const int frag = t >> 6;             // 0 .. 2303
  const int nt = frag & 3;
  const int q = frag >> 2;
  const int ks = q % 24;
  const int q2 = q / 24;
  const int h = q2 & 7;
  const int mod = q2 >> 3;
  const int n16 = h * 4 + nt;
  const float* __restrict__ W = (mod == 0) ? Wi : ((mod == 1) ? Wc : Wd);

  const int n = n16 * 16 + (l & 15);
  const int r = n >> 3;
  const int c = n & 7;
  const int i0 = ks * 32 + (l >> 4) * 8;
  const float* src = W + (size_t)(c * 64 + r) * 768 + i0;
  floatx4 f0 = *(const floatx4*)(src);
  floatx4 f1 = *(const floatx4*)(src + 4);
  uintx4 p;
  p.x = pk_bf16(f0.x, f0.y);
  p.y = pk_bf16(f0.z, f0.w);
  p.z = pk_bf16(f1.x, f1.y);
  p.w = pk_bf16(f1.z, f1.w);
  Bprep[(size_t)frag * 64 + l] = p;

  if (t < 1536) {
    const int m2 = t >> 9;
    const int nn = t & 511;
    const float* bb = (m2 == 0) ? bi : ((m2 == 1) ? bc : bd);
    biasPrep[t] = bb[(nn & 7) * 64 + (nn >> 3)];
  }
}

// ============================================================
// Fused GEMM + squash. ROUND-13 = round-11 kernel (81.4 us verified)
// + per-wave K-step stagger (wv*3, modular) to break wave convoying.
//   Block: 512 thr / 8 waves; wave owns 32x64 (acc[2][4] = 32 AGPR).
//   A (32x768) staged once as bf16 frags in 48 KB LDS (slot-XOR), one
//   barrier, 24-step K-loop, 3-deep register prefetch, 7x3 + 3 drain.
//   Epilogue: shuffle-squash + rsq/rcp + proven 1.0x store geometry.
//   Grid 1536 = 3 mods x 512 m-tiles (XCD swizzle 8x192).
// ============================================================
#define LOADA(aa, kk)                                                        \
  {                                                                          \
    _Pragma("unroll") for (int mt = 0; mt < 2; ++mt)                         \
        aa[mt] = Afr[((kk) * 2 + mt) * 64 +                                  \
                     ((ln ^ (((kk) * 4 + quad) & 15)) + (quad << 4))];       \
  }

#define LOADB(bb, kk)                                                        \
  {                                                                          \
    _Pragma("unroll") for (int n2 = 0; n2 < 4; ++n2)                         \
        bb[n2] = bbase[(size_t)((kk) * 4 + n2) * 64];                        \
  }

#define COMP(aa, bb)                                                     \
  {                                                                      \
    _Pragma("unroll") for (int mt = 0; mt < 2; ++mt)                     \
    {                                                                    \
      short8 af = __builtin_bit_cast(short8, aa[mt]);                    \
      _Pragma("unroll") for (int n2 = 0; n2 < 4; ++n2)                   \
          acc[mt][n2] = __builtin_amdgcn_mfma_f32_16x16x32_bf16(         \
              af, __builtin_bit_cast(short8, bb[n2]), acc[mt][n2], 0, 0, \
              0);                                                        \
    }                                                                    \
  }

#define INCW(u) { u = (u == 23) ? 0 : (u + 1); }

__global__ __launch_bounds__(512, 4) void caps_fused(
    const float* __restrict__ x0, const float* __restrict__ x1, const float* __restrict__ x2,
    const uintx4* __restrict__ Bprep, const float* __restrict__ biasPrep,
    float* __restrict__ out) {
  __shared__ unsigned long long As64[48 * 128];  // 48 frags x 64 slots x 16 B

  const int tid = threadIdx.x;
  // XCD-chunk swizzle: 1536 = 8 XCDs x 192 contiguous blocks (bijective).
  const int bx0 = blockIdx.x;
  const int bx = (bx0 & 7) * 192 + (bx0 >> 3);
  const int mod = bx >> 9;           // 1536 = 3 x 512
  const int bm = bx & 511;           // m-tile (32 rows)
  const float* __restrict__ X = (mod == 0) ? x0 : ((mod == 1) ? x1 : x2);

  // ---- one-shot staging: 32 rows x 768 cols fp32, coalesced, 512 thr ----
  const float* src = X + (size_t)bm * 32 * 768;
#pragma unroll
  for (int i = 0; i < 12; ++i) {
    const int idx = i * 2048 + tid * 4;          // flat float index in tile
    floatx4 f = *(const floatx4*)(src + idx);
    const int m = (unsigned)idx / 768u;
    const int k = idx - m * 768;
    const int ks = k >> 5;
    const int kk = k & 31;
    const int qk = kk >> 3;                      // quad of k
    const int jh = (kk >> 2) & 1;                // which 8-byte half
    const int mt = m >> 4;
    const int lnn = m & 15;
    const int p = (ks * 4 + qk) & 15;            // slot-XOR spread
    const int slot = (lnn ^ p) + (qk << 4);
    unsigned long long w =
        ((unsigned long long)pk_bf16(f.z, f.w) << 32) | pk_bf16(f.x, f.y);
    As64[(((ks * 2 + mt) * 64 + slot) << 1) + jh] = w;
  }
  __syncthreads();  // the ONLY barrier

  const int lane = tid & 63;
  const int ln = lane & 15;
  const int quad = lane >> 4;
  const int wv = tid >> 6;  // wave id 0..7 == h: n16-range wv*4 .. wv*4+3

  const uintx4* Afr = (const uintx4*)As64;
  const uintx4* bbase = Bprep + (size_t)(mod * 8 + wv) * (96 * 64) + lane;

  floatx4 acc[2][4] = {};
  uintx4 a0[2], a1[2], a2[2], b0[4], b1[4], b2[4];

  // per-wave K-start stagger: decorrelate the 8 waves' load bursts
  int u = wv * 3;
  LOADA(a0, u); LOADB(b0, u); INCW(u);
  LOADA(a1, u); LOADB(b1, u); INCW(u);
  LOADA(a2, u); LOADB(b2, u); INCW(u);
#pragma unroll 1
  for (int it = 0; it < 7; ++it) {
    COMP(a0, b0);
    LOADA(a0, u); LOADB(b0, u); INCW(u);
    COMP(a1, b1);
    LOADA(a1, u); LOADB(b1, u); INCW(u);
    COMP(a2, b2);
    LOADA(a2, u); LOADB(b2, u); INCW(u);
  }
  COMP(a0, b0);   // drain: last three staggered steps
  COMP(a1, b1);
  COMP(a2, b2);

  // ---- epilogue: bias + squash (8 capsule lanes share s) + store ----
  const int col0 = mod * 512 + wv * 64 + ln;
  float bias[4];
#pragma unroll
  for (int n2 = 0; n2 < 4; ++n2) bias[n2] = biasPrep[col0 + n2 * 16];

#pragma unroll
  for (int mt = 0; mt < 2; ++mt) {
    const size_t rbase = (size_t)(bm * 32 + mt * 16 + quad * 4) * 1536;
#pragma unroll
    for (int n2 = 0; n2 < 4; ++n2) {
      float* op = out + rbase + col0 + n2 * 16;
#pragma unroll
      for (int jj = 0; jj < 4; ++jj) {
        float uo = acc[mt][n2][jj] + bias[n2];
        float s = uo * uo;
        s += __shfl_xor(s, 1);
        s += __shfl_xor(s, 2);
        s += __shfl_xor(s, 4);
#if __has_builtin(__builtin_amdgcn_rsqf) && __has_builtin(__builtin_amdgcn_rcpf)
        float sc = s * __builtin_amdgcn_rsqf(s + 1e-7f) *
                   __builtin_amdgcn_rcpf(1.0f + s);
#else
        float sc = s / ((1.0f + s) * sqrtf(s + 1e-7f));
#endif
        op[(size_t)jj * 1536] = uo * sc;
      }
    }
  }
}

// ============================================================
extern "C" void kernel_launch(void* const* d_in, const int* in_sizes, int n_in,
                              void* d_out, int out_size, void* d_ws, size_t ws_size,
                              hipStream_t stream) {
  const float* ximg = (const float*)d_in[0];
  const float* xcapt = (const float*)d_in[1];
  const float* xdct = (const float*)d_in[2];
  const float* Wi = (const float*)d_in[3];
  const float* bi = (const float*)d_in[4];
  const float* Wc = (const float*)d_in[5];
  const float* bc = (const float*)d_in[6];
  const float* Wd = (const float*)d_in[7];
  const float* bd = (const float*)d_in[8];

  uintx4* Bprep = (uintx4*)d_ws;                           // 2.25 MiB
  float* biasPrep = (float*)((char*)d_ws + 2304 * 1024);   // 6 KiB

  hipLaunchKernelGGL(prep_w, dim3(576), dim3(256), 0, stream,
                     Wi, Wc, Wd, bi, bc, bd, Bprep, biasPrep);
  hipLaunchKernelGGL(caps_fused, dim3(1536), dim3(512), 0, stream,
                     ximg, xcapt, xdct, (const uintx4*)Bprep, biasPrep,
                     (float*)d_out);
}